// Round 1
// 871.672 us; speedup vs baseline: 2.6470x; 2.6470x over previous
//
#include <hip/hip_runtime.h>
#include <cstdint>
#include <cstddef>

#define B_   8
#define V_   50000
#define C_   256
#define K_   9
#define PC   64
#define M_   64                 // rows per block

typedef __attribute__((ext_vector_type(8))) short          bf16x8;
typedef __attribute__((ext_vector_type(4))) float          f32x4;
typedef __attribute__((ext_vector_type(4))) unsigned short us4;

// ---- workspace layout (ushort units); total 204800 ushorts = 409600 B ----
#define W1_ELEMS (PC * PC * K_)      // 36864  (64 out x 576 in)
#define W2_ELEMS (C_ * C_)           // 65536
#define W1H 0
#define W1L W1_ELEMS
#define W2H (2 * W1_ELEMS)
#define W2L (2 * W1_ELEMS + W2_ELEMS)

// split fp32 -> hi/lo bf16 (truncation; r = a - hi is exact, residual ~2^-16 rel)
__device__ __forceinline__ void splitf(float a, unsigned short &h, unsigned short &l)
{
    unsigned u = __float_as_uint(a);
    h = (unsigned short)(u >> 16);
    float r = a - __uint_as_float(u & 0xffff0000u);
    l = (unsigned short)(__float_as_uint(r) >> 16);
}

// ---------------------------------------------------------------------------
// Pack W1/W2 into per-lane MFMA B-fragment order, hi/lo bf16 split.
// Fragment (nt,ks): lane l supplies B[k][n], n = nt*16+(l&15),
// k = ks*32+(l>>4)*8+j, stored at ((nt*KS+ks)*64+l)*8+j  -> wave reads are
// contiguous 1 KB streams.
// ---------------------------------------------------------------------------
__global__ __launch_bounds__(256) void prep_w(
    const float* __restrict__ W1, const float* __restrict__ W2,
    unsigned short* __restrict__ ws)
{
    int e = blockIdx.x * 256 + threadIdx.x;
    if (e < W1_ELEMS) {                       // W1: 4 col-tiles x 18 k-steps
        int nt  = e / 9216;
        int rem = e - nt * 9216;
        int ks  = rem >> 9;
        int l   = (rem >> 3) & 63;
        int j   = rem & 7;
        int n   = nt * 16 + (l & 15);
        int k   = ks * 32 + ((l >> 4) << 3) + j;
        unsigned short h, lo;
        splitf(W1[n * (K_ * PC) + k], h, lo);
        ws[W1H + e] = h;
        ws[W1L + e] = lo;
    } else if (e < W1_ELEMS + W2_ELEMS) {     // W2: 16 col-tiles x 8 k-steps
        int e2  = e - W1_ELEMS;
        int nt  = e2 >> 12;
        int rem = e2 & 4095;
        int ks  = rem >> 9;
        int l   = (rem >> 3) & 63;
        int j   = rem & 7;
        int n   = nt * 16 + (l & 15);
        int k   = ks * 32 + ((l >> 4) << 3) + j;
        unsigned short h, lo;
        splitf(W2[n * C_ + k], h, lo);
        ws[W2H + e2] = h;
        ws[W2L + e2] = lo;
    }
}

// ---------------------------------------------------------------------------
// Fused: gather -> GEMM1(576->64) -> concat -> GEMM2(256->256), all split-bf16
// MFMA (hi*Bh + lo*Bh + hi*Bl). 64 rows/block, 4 waves.
// MFMA 16x16x32 layouts: A[l&15][(l>>4)*8+j], B[(l>>4)*8+j][l&15],
// D col=l&15, row=(l>>4)*4+reg (m89-verified).
// LDS XOR swizzle byte^=((row&7)<<4) on all A-tiles (T2 condition holds:
// lanes read different rows at same col slot; 128/512-B row strides).
// ---------------------------------------------------------------------------
__global__ __launch_bounds__(256, 2) void fused_mfma(
    const float* __restrict__ x, const int* __restrict__ idx,
    const float* __restrict__ b1, const float* __restrict__ b2,
    const unsigned short* __restrict__ ws, float* __restrict__ out)
{
    // XC = x_cat tile (hi/lo). First 8 KB of each also aliases the gather
    // A-chunk (64 rows x 64 ch) during GEMM1; all reuse is barrier-separated.
    __shared__ alignas(16) unsigned short XCh[M_ * C_];   // 32 KB
    __shared__ alignas(16) unsigned short XCl[M_ * C_];   // 32 KB
    __shared__ int idxs[M_][K_];                          // 2.25 KB  -> 2 blocks/CU

    const int tid  = threadIdx.x;
    const int lane = tid & 63;
    const int wv   = tid >> 6;
    const int rowBase = blockIdx.x * M_;

    for (int e = tid; e < M_ * K_; e += 256) {
        int r  = e / K_;
        int kk = e - r * K_;
        idxs[r][kk] = idx[((rowBase + r) % V_) * K_ + kk];
    }
    __syncthreads();

    const int lo16 = lane & 15;
    const int hi4  = lane >> 4;
    const int acol = hi4 << 3;              // A-frag k offset
    const int swzl = (lane & 7) << 4;       // (row&7)<<4 for rows rt*16+lo16

    // GEMM1: wave -> 2x2 tile block (A and B each read 2x, balances LDS vs L2)
    const int rtb = (wv >> 1) << 1;         // row-tile base: 0 or 2
    const int ntb = (wv & 1) << 1;          // col-tile base: 0 or 2

    f32x4 acc1[2][2];
    #pragma unroll
    for (int i = 0; i < 2; ++i)
        #pragma unroll
        for (int j = 0; j < 2; ++j)
            acc1[i][j] = (f32x4){0.f, 0.f, 0.f, 0.f};

    // gather mapping: 16 lanes x 4 ch-floats per row, rows tid>>4 + 16j
    const int gc  = (tid & 15) << 2;
    const int gr0 = tid >> 4;

    int vb[4];                              // b*V_ per gathered row (hoisted div)
    #pragma unroll
    for (int j = 0; j < 4; ++j)
        vb[j] = ((rowBase + gr0 + 16 * j) / V_) * V_;

    const bf16x8* Wp1h = (const bf16x8*)(ws + W1H);
    const bf16x8* Wp1l = (const bf16x8*)(ws + W1L);

    // prefetch gather chunk 0 into registers (next-chunk loads issue before the
    // barrier each iteration so HBM/L2 latency hides under GEMM1 compute)
    f32x4 gbuf[4];
    #pragma unroll
    for (int j = 0; j < 4; ++j)
        gbuf[j] = *(const f32x4*)(x + (size_t)(vb[j] + idxs[gr0 + 16 * j][0]) * C_ + gc);

    for (int k = 0; k < K_; ++k) {
        // ---- store gathered chunk (split + swizzled) ----
        #pragma unroll
        for (int j = 0; j < 4; ++j) {
            int r = gr0 + 16 * j;
            unsigned short h0,h1,h2,h3,l0,l1,l2,l3;
            splitf(gbuf[j][0], h0, l0);
            splitf(gbuf[j][1], h1, l1);
            splitf(gbuf[j][2], h2, l2);
            splitf(gbuf[j][3], h3, l3);
            int byteoff = ((r * PC + gc) * 2) ^ ((r & 7) << 4);
            *(us4*)((char*)XCh + byteoff) = (us4){h0, h1, h2, h3};
            *(us4*)((char*)XCl + byteoff) = (us4){l0, l1, l2, l3};
        }
        if (k + 1 < K_) {
            #pragma unroll
            for (int j = 0; j < 4; ++j)
                gbuf[j] = *(const f32x4*)(x + (size_t)(vb[j] + idxs[gr0 + 16 * j][k + 1]) * C_ + gc);
        }
        __syncthreads();

        // ---- GEMM1 accumulate: 2 k-steps of 32 ----
        #pragma unroll
        for (int ks2 = 0; ks2 < 2; ++ks2) {
            int ksg = k * 2 + ks2;
            bf16x8 ah[2], al[2], bh[2], bl[2];
            #pragma unroll
            for (int i = 0; i < 2; ++i) {
                int abyte = ((((rtb + i) * 16 + lo16) * PC + ks2 * 32 + acol) * 2) ^ swzl;
                ah[i] = *(const bf16x8*)((const char*)XCh + abyte);
                al[i] = *(const bf16x8*)((const char*)XCl + abyte);
                bh[i] = Wp1h[((ntb + i) * 18 + ksg) * 64 + lane];
                bl[i] = Wp1l[((ntb + i) * 18 + ksg) * 64 + lane];
            }
            #pragma unroll
            for (int i = 0; i < 2; ++i)
                #pragma unroll
                for (int j = 0; j < 2; ++j) {
                    acc1[i][j] = __builtin_amdgcn_mfma_f32_16x16x32_bf16(ah[i], bh[j], acc1[i][j], 0, 0, 0);
                    acc1[i][j] = __builtin_amdgcn_mfma_f32_16x16x32_bf16(al[i], bh[j], acc1[i][j], 0, 0, 0);
                    acc1[i][j] = __builtin_amdgcn_mfma_f32_16x16x32_bf16(ah[i], bl[j], acc1[i][j], 0, 0, 0);
                }
        }
        __syncthreads();   // A-chunk reads done before next overwrite
    }

    // ---- build x_cat: p (+b1) into ch 0..63, x untouched into ch 64..255 ----
    #pragma unroll
    for (int i = 0; i < 2; ++i)
        #pragma unroll
        for (int j = 0; j < 2; ++j) {
            int c = (ntb + j) * 16 + lo16;
            float bb = b1[c];
            #pragma unroll
            for (int reg = 0; reg < 4; ++reg) {
                int r = (rtb + i) * 16 + hi4 * 4 + reg;
                unsigned short h, lo;
                splitf(acc1[i][j][reg] + bb, h, lo);
                int byteoff = ((r * C_ + c) * 2) ^ ((r & 7) << 4);
                *(unsigned short*)((char*)XCh + byteoff) = h;
                *(unsigned short*)((char*)XCl + byteoff) = lo;
            }
        }

    #pragma unroll
    for (int j = 0; j < 12; ++j) {           // 64 rows x 192 ch, float4 each
        int e = j * 256 + tid;
        int r = e / 48;
        int c = PC + (e - r * 48) * 4;
        f32x4 g = *(const f32x4*)(x + (size_t)(rowBase + r) * C_ + c);
        unsigned short h0,h1,h2,h3,l0,l1,l2,l3;
        splitf(g[0], h0, l0);
        splitf(g[1], h1, l1);
        splitf(g[2], h2, l2);
        splitf(g[3], h3, l3);
        int byteoff = ((r * C_ + c) * 2) ^ ((r & 7) << 4);
        *(us4*)((char*)XCh + byteoff) = (us4){h0, h1, h2, h3};
        *(us4*)((char*)XCl + byteoff) = (us4){l0, l1, l2, l3};
    }
    __syncthreads();

    // ---- GEMM2: wave owns col-tiles 4wv..4wv+3, all 4 row-tiles ----
    // (W2 fragments read exactly once per block -> no intra-block L2 redundancy)
    const bf16x8* Wp2h = (const bf16x8*)(ws + W2H);
    const bf16x8* Wp2l = (const bf16x8*)(ws + W2L);

    f32x4 acc2[4][4];                        // [ntl][rt]
    #pragma unroll
    for (int i = 0; i < 4; ++i)
        #pragma unroll
        for (int j = 0; j < 4; ++j)
            acc2[i][j] = (f32x4){0.f, 0.f, 0.f, 0.f};

    #pragma unroll 2
    for (int ks = 0; ks < 8; ++ks) {
        bf16x8 ah[4], al[4];
        #pragma unroll
        for (int rt = 0; rt < 4; ++rt) {
            int abyte = (((rt * 16 + lo16) * C_ + ks * 32 + acol) * 2) ^ swzl;
            ah[rt] = *(const bf16x8*)((const char*)XCh + abyte);
            al[rt] = *(const bf16x8*)((const char*)XCl + abyte);
        }
        #pragma unroll
        for (int ntl = 0; ntl < 4; ++ntl) {
            int nt = 4 * wv + ntl;
            bf16x8 bh = Wp2h[(nt * 8 + ks) * 64 + lane];
            bf16x8 bl = Wp2l[(nt * 8 + ks) * 64 + lane];
            #pragma unroll
            for (int rt = 0; rt < 4; ++rt) {
                acc2[ntl][rt] = __builtin_amdgcn_mfma_f32_16x16x32_bf16(ah[rt], bh, acc2[ntl][rt], 0, 0, 0);
                acc2[ntl][rt] = __builtin_amdgcn_mfma_f32_16x16x32_bf16(al[rt], bh, acc2[ntl][rt], 0, 0, 0);
                acc2[ntl][rt] = __builtin_amdgcn_mfma_f32_16x16x32_bf16(ah[rt], bl, acc2[ntl][rt], 0, 0, 0);
            }
        }
    }

    // ---- epilogue: +b2, nontemporal store (keep LLC for the gather slab) ----
    #pragma unroll
    for (int ntl = 0; ntl < 4; ++ntl) {
        int c = (4 * wv + ntl) * 16 + lo16;
        float bb = b2[c];
        #pragma unroll
        for (int rt = 0; rt < 4; ++rt)
            #pragma unroll
            for (int reg = 0; reg < 4; ++reg) {
                int r = rt * 16 + hi4 * 4 + reg;
                __builtin_nontemporal_store(acc2[ntl][rt][reg] + bb,
                                            out + (size_t)(rowBase + r) * C_ + c);
            }
    }
}

// ---------------------------------------------------------------------------
extern "C" void kernel_launch(void* const* d_in, const int* in_sizes, int n_in,
                              void* d_out, int out_size, void* d_ws, size_t ws_size,
                              hipStream_t stream)
{
    const float* x  = (const float*)d_in[0];
    const int*   idx = (const int*)d_in[1];   // int64 in reference -> int32 on device
    const float* W1 = (const float*)d_in[2];
    const float* b1 = (const float*)d_in[3];
    const float* W2 = (const float*)d_in[4];
    const float* b2 = (const float*)d_in[5];
    float* out = (float*)d_out;
    unsigned short* ws = (unsigned short*)d_ws;   // needs 409600 B

    prep_w<<<(W1_ELEMS + W2_ELEMS) / 256, 256, 0, stream>>>(W1, W2, ws);
    fused_mfma<<<(B_ * V_) / M_, 256, 0, stream>>>(x, idx, b1, b2, ws, out);
}